// Round 4
// baseline (153.277 us; speedup 1.0000x reference)
//
#include <hip/hip_runtime.h>
#include <hip/hip_bf16.h>

// B=8, H=W=1024, N=4096, R=8 -> d=17, patch=289, out (B,4096,578) fp32.
// p1[b,n,j] = image1[b, m1 + j%17 - 8, m0 + j//17 - 8]  (zero-pad OOB)
// p2[b,n,j] = image2[b, m3 + j%17 - 8, m2 + j//17 - 8]
// normalize each 289-vector: (p - mean) / (std_ddof1 + 1e-4)
//
// R4 structure: one wave per patch. LOAD phase is memory-coalesced:
// lanes 0..50 = 3 groups x 17 lanes; group loads one image-row segment
// (17 contiguous floats) -> ~6-9 cache lines per wave instruction instead
// of 64 (row-strided gather was address-divergence bound at 57.6 us).
// Values go to LDS at output position j = r + 17*c; sum/sumsq accumulated
// during load (order-independent); store phase reads LDS in output order
// (stride 64 -> 2-way bank aliasing, free) and writes coalesced.

#define IMG_H 1024
#define IMG_W 1024
#define NMATCH 4096
#define DPATCH 17
#define NPATCH 289
#define RAD 8

__global__ __launch_bounds__(256) void extract_patch_kernel(
    const float* __restrict__ img1,
    const float* __restrict__ img2,
    const int* __restrict__ matches,
    float* __restrict__ out)
{
    __shared__ float smem[4 * NPATCH];   // 4 waves/block x 289 floats

    const int tid  = blockIdx.x * blockDim.x + threadIdx.x;
    const int wave = tid >> 6;          // global wave id: 0 .. 65535
    const int lane = tid & 63;
    const int pair  = wave >> 1;        // b*4096 + n : 0 .. 32767
    const int which = wave & 1;         // 0 -> img1, 1 -> img2
    const int wbase = (threadIdx.x >> 6) * NPATCH;

    // match coords (wave-uniform scalar loads, broadcast)
    const int* m = matches + pair * 4;
    const int mx = m[which ? 2 : 0];
    const int my = m[which ? 3 : 1];

    const int b = pair >> 12;           // pair / 4096
    const float* __restrict__ imgb =
        (which ? img2 : img1) + (size_t)b * (IMG_H * IMG_W);

    // ---- coalesced load phase ----
    const int g = lane / DPATCH;        // row-group 0..2 (3 = idle lanes 51..63)
    const int c = lane - g * DPATCH;    // column within patch row segment, 0..16
    const int ix = mx + c - RAD;        // image column (contiguous across lanes)
    const bool col_ok = (g < 3) && ((unsigned)ix < IMG_W);

    float sum = 0.f, sumsq = 0.f;
#pragma unroll
    for (int it = 0; it < 6; ++it) {
        const int r = it * 3 + g;       // patch row 0..17 (17 -> idle)
        float val = 0.f;
        if (g < 3 && r < DPATCH) {
            const int iy = my + r - RAD;
            if (col_ok && (unsigned)iy < IMG_H) {
                val = imgb[iy * IMG_W + ix];
            }
            smem[wbase + r + DPATCH * c] = val;   // output position j = r + 17c
        }
        sum   += val;
        sumsq += val * val;
    }

    // wave-64 butterfly reduction
#pragma unroll
    for (int off = 32; off > 0; off >>= 1) {
        sum   += __shfl_xor(sum,   off, 64);
        sumsq += __shfl_xor(sumsq, off, 64);
    }

    const float mean = sum * (1.0f / 289.0f);
    float var = (sumsq - 289.0f * mean * mean) * (1.0f / 288.0f);
    var = fmaxf(var, 0.0f);
    const float inv = 1.0f / (sqrtf(var) + 1e-4f);

    // ---- coalesced store phase (LDS read in output order) ----
    float* __restrict__ o = out + (size_t)pair * 578 + which * NPATCH;
#pragma unroll
    for (int k = 0; k < 5; ++k) {
        const int j = lane + (k << 6);
        if (j < NPATCH) {
            o[j] = (smem[wbase + j] - mean) * inv;
        }
    }
}

extern "C" void kernel_launch(void* const* d_in, const int* in_sizes, int n_in,
                              void* d_out, int out_size, void* d_ws, size_t ws_size,
                              hipStream_t stream) {
    const float* img1  = (const float*)d_in[0];
    const float* img2  = (const float*)d_in[1];
    const int* matches = (const int*)d_in[2];
    float* out         = (float*)d_out;

    // 8 * 4096 pairs * 2 images = 65536 waves; 4 waves (patches) per block
    const int n_waves = 8 * NMATCH * 2;
    dim3 block(256);
    dim3 grid(n_waves * 64 / 256);
    hipLaunchKernelGGL(extract_patch_kernel, grid, block, 0, stream,
                       img1, img2, matches, out);
}